// Round 9
// baseline (151.433 us; speedup 1.0000x reference)
//
#include <hip/hip_runtime.h>

#define N_    64
#define HW_   240
#define H1_   120
#define H2_   60
#define C0_   3
#define C1_   32
#define C2_   64
#define C3_   128
#define HEAD_ 1280

typedef unsigned short US;
typedef short bf16x8 __attribute__((ext_vector_type(8)));
typedef float f32x16 __attribute__((ext_vector_type(16)));

__device__ __forceinline__ US f2bf(float f) {
  union { float f; unsigned u; } v; v.f = f;
  unsigned r = v.u + 0x7FFF + ((v.u >> 16) & 1);  // RNE
  return (US)(r >> 16);
}

// h1q parity-split padded NHWC bf16: [n][row 122][parity 2][xh 62][32ch].
// h1 pixel (gy,gx): row = gy+1; gx even=2m -> plane0[m]; gx odd=2m-1 -> plane1[m].
// Pad liveness (audited R8): k2 reads rows 0..120 only; live pads = row 0 +
// p1 m=0 chunk of rows 1..120 — written by k1; k0 doesn't touch h1q.
#define H1Q_ROW 3968
#define H1Q_PL  1984

__device__ __forceinline__ void gld_lds16(const void* g, void* l) {
  __builtin_amdgcn_global_load_lds(
      (const __attribute__((address_space(1))) unsigned int*)g,
      (__attribute__((address_space(3))) unsigned int*)l, 16, 0, 0);
}

// ---------------------------------------------------------------------------
// K0 (R8): weight prep + gap zero ONLY.
// ---------------------------------------------------------------------------
__global__ __launch_bounds__(256) void k0_prep(
    const float* __restrict__ w1, const float* __restrict__ w2,
    const float* __restrict__ w0,
    US* __restrict__ wt1, US* __restrict__ wt2,
    US* __restrict__ wt0, float* __restrict__ gap) {
  int gid = blockIdx.x * 256 + threadIdx.x;
  if (gid < 18432) {
    int e = gid;                              // w1 flat [oc][ic][ky][kx]
    int oc = e / 288, ic = (e / 9) % 32, ky = (e / 3) % 3, kx = e % 3;
    wt1[((ky * 3 + kx) * 64 + oc) * 32 + ic] = f2bf(w1[e]);
  } else if (gid < 18432 + 8192) {
    int e = gid - 18432;
    wt2[e] = f2bf(w2[e]);
  } else if (gid < 18432 + 8192 + 1024) {
    int e = gid - (18432 + 8192);             // e = oc*32 + k
    int oc = e >> 5, k = e & 31;
    wt0[e] = (k < 27) ? f2bf(w0[oc * 27 + k]) : (US)0;
  } else if (gid < 18432 + 8192 + 1024 + 8192) {
    gap[gid - (18432 + 8192 + 1024)] = 0.f;
  }
}

// ---------------------------------------------------------------------------
// K1 (R8 exact): stem conv 3->32 via MFMA im2col, 1 output row per block,
// global_load_lds x staging, pad-writing. Grid (121, 64).
// ---------------------------------------------------------------------------
#define XSW 248
__global__ __launch_bounds__(256) void k1_mfma(
    const float* __restrict__ x, const US* __restrict__ wt0,
    const float* __restrict__ alpha, const float* __restrict__ beta,
    US* __restrict__ h1q) {
  __shared__ __align__(16) float xs[3 * 3 * XSW];  // [seg=ic*3+r][248]
  __shared__ US ot[128 * 32];         // [px][oc] bf16
  int y = blockIdx.x, n = blockIdx.y;
  int t = threadIdx.x, w = t >> 6, l = t & 63;

  if (y == 120) {                     // zero pad row 0 (whole row, 3968 US)
    uint4 z; z.x = z.y = z.z = z.w = 0u;
    long base = (long)(n * 122) * H1Q_ROW;
    for (int u = t; u < 496; u += 256)
      *(uint4*)(h1q + base + (long)u * 8) = z;
    return;
  }

  long rowb = ((long)(n * 122 + y + 1)) * H1Q_ROW;
  if (t < 4) {                        // zero own row's p1 m=0 pad chunk
    uint4 z; z.x = z.y = z.z = z.w = 0u;
    *(uint4*)(h1q + rowb + H1Q_PL + t * 8) = z;
  }

  int iy0 = 2 * y - 1;
  const float* xn = x + (long)n * C0_ * HW_ * HW_;

  // boundary zeros: cols 0..3 and 244..247 per seg
  if (t < 18) {
    int seg = t >> 1, end = t & 1;
    float4 z; z.x = z.y = z.z = z.w = 0.f;
    *(float4*)(xs + seg * XSW + (end ? 244 : 0)) = z;
  }
  // iy<0 rows (only y==0, segs r==0): pre-zero interior
  if (y == 0) {
    float4 z; z.x = z.y = z.z = z.w = 0.f;
    for (int e = t; e < 180; e += 256) {
      int m = e % 60, icz = e / 60;
      *(float4*)(xs + (icz * 3) * XSW + 4 + 4 * m) = z;
    }
  }
  __syncthreads();   // zeros visible before async staging overlaps

  // async stage: seg (wave-uniform) = w, w+4, w+8; 60 lanes x 16 B each
  for (int sgi = w; sgi < 9; sgi += 4) {
    int ic = sgi / 3, r = sgi - (sgi / 3) * 3;
    int iy = iy0 + r;                  // wave-uniform
    if (iy >= 0 && l < 60)
      gld_lds16((const char*)(xn + (long)ic * HW_ * HW_ + (long)iy * HW_) +
                    l * 16,
                (char*)(xs + sgi * XSW + 4) + l * 16);
  }
  __syncthreads();   // drains vmcnt

  int wv = w;
  int lane31 = l & 31, half = l >> 5;
  int ox = wv * 32 + lane31;
  int oxc = ox < H1_ ? ox : (H1_ - 1);

  // A fragments: k = m*16 + half*8 + j; value = xs[seg(k)][3 + 2*oxc + kx]
  float fa[16];
#pragma unroll
  for (int m = 0; m < 2; m++)
#pragma unroll
    for (int j = 0; j < 8; j++) {
      int k = m * 16 + half * 8 + j;
      float v = 0.f;
      if (k < 27) {
        int ic = k / 9, rem = k - ic * 9;
        int ky = rem / 3, kx = rem - ky * 3;
        v = xs[(ic * 3 + ky) * XSW + 3 + 2 * oxc + kx];
      }
      fa[m * 8 + j] = v;
    }
  bf16x8 a0, a1;
#pragma unroll
  for (int j = 0; j < 8; j++) {
    a0[j] = (short)f2bf(fa[j]);
    a1[j] = (short)f2bf(fa[8 + j]);
  }
  const US* wb = wt0 + lane31 * 32 + half * 8;   // oc = lane31
  bf16x8 b0 = *(const bf16x8*)(wb);
  bf16x8 b1 = *(const bf16x8*)(wb + 16);

  f32x16 acc;
#pragma unroll
  for (int i = 0; i < 16; i++) acc[i] = 0.f;
  acc = __builtin_amdgcn_mfma_f32_32x32x16_bf16(a0, b0, acc, 0, 0, 0);
  acc = __builtin_amdgcn_mfma_f32_32x32x16_bf16(a1, b1, acc, 0, 0, 0);

  int oc = lane31;
  float al = alpha[oc], be = beta[oc];
#pragma unroll
  for (int r = 0; r < 16; r++) {
    int row = (r & 3) + 8 * (r >> 2) + 4 * half;   // px within tile
    float v = fmaxf(fmaf(acc[r], al, be), 0.f);
    ot[(wv * 32 + row) * 32 + oc] = f2bf(v);
  }
  __syncthreads();

  // store 120 px * 64 B as parity-split full chunks; 480 uint4 total
  for (int u = t; u < 480; u += 256) {
    int px = u >> 2, q = u & 3;
    int pl = px & 1;
    int m = (px + 1) >> 1;
    long addr = rowb + (pl ? H1Q_PL : 0) + (long)m * 32 + q * 8;
    *(uint4*)(h1q + addr) = *(const uint4*)(ot + px * 32 + q * 8);
  }
}

// ---------------------------------------------------------------------------
// K2 (R9): ring-5 @ 3 blocks/CU, wB UN-HOISTED (the R6 retest, confound
// removed). grid (8,96) = 768 = 3/CU, bound (256,3) caps VGPR ~168; wA (72
// VGPR) stays hoisted, wB read per-iter from L2-resident wt2 (16 KB) so the
// working set fits the cap (est ~138 VGPR, no spill). Ring-5 slot audit:
// live window {2y..2y+4} distinct mod 5; prefetch slots (2y+3)%5,(2y+4)%5
// disjoint from compute {2y..2y+2}%5. LDS 40960+9216 = 50176 -> 3 blocks/CU.
// ---------------------------------------------------------------------------
#define TS 72
__global__ __launch_bounds__(256, 3) void k2_fused(
    const US* __restrict__ h1q, const US* __restrict__ wt1,
    const US* __restrict__ wt2,
    const float* __restrict__ a1, const float* __restrict__ b1,
    const float* __restrict__ a2, const float* __restrict__ b2,
    float* __restrict__ gap) {
  __shared__ __align__(16) US st[5 * 4096];    // 40960 B: 5 row-slots (swz)
  __shared__ __align__(16) US tile[64 * TS];   // 9216 B: conv2 out [px][oc]
  int t = threadIdx.x, w = t >> 6, l = t & 63;
  int lane31 = l & 31, half = l >> 5;

  // XCD x (= blockIdx.x, x-major dispatch) handles n in [8x, 8x+8)
  int n = 8 * blockIdx.x + (blockIdx.y & 7);
  int bxr = blockIdx.y >> 3;                   // row-group 0..11
  int y0 = bxr * 5;                            // 5 rows per group

  const char* nb = (const char*)(h1q + (long)(n * 122) * H1Q_ROW);

  // ---- hoist wA + BN params (wB deliberately NOT hoisted) ----
  int wm = w & 1, wn = w >> 1;                 // stage-A roles
  int oc = wn * 32 + lane31;
  int pt = w & 1, og = w >> 1;                 // conv3 roles
  bf16x8 wA[9][2];
#pragma unroll
  for (int kk = 0; kk < 9; kk++)
#pragma unroll
    for (int c = 0; c < 2; c++)
      wA[kk][c] = *(const bf16x8*)(wt1 + (kk * 64 + oc) * 32 + half * 8 + c * 16);
  float al2[2], be2[2];
#pragma unroll
  for (int nt = 0; nt < 2; nt++) {
    int oc2 = (og * 2 + nt) * 32 + lane31;
    al2[nt] = a2[oc2]; be2[nt] = b2[oc2];
  }
  float al1 = a1[oc], be1 = b1[oc];

  // per-thread invariant A-read offsets (swizzled, within-row US units)
  int px = wm * 32 + lane31;
  int xx = px < 60 ? px : 59;
  int abase = xx * 32 + half * 8;
  int usofs[3][2];
#pragma unroll
  for (int kx = 0; kx < 3; kx++)
#pragma unroll
    for (int c = 0; c < 2; c++) {
      int uo = (kx == 1 ? 0 : (kx == 0 ? 1984 : 2016)) + abase + c * 16;
      usofs[kx][c] = uo ^ (((uo >> 6) & 7) << 3);
    }

  // ---- prologue: stage rows 2y0..2y0+2, 512 chunks (8 KB) per row ----
#pragma unroll
  for (int i = 0; i < 6; i++) {
    int c = i * 256 + t;                  // 1536 = 3 rows * 512 chunks
    int rw = c >> 9;                      // wave-uniform (512 % 64 == 0)
    int b = (c & 511) * 16;
    int sb = b ^ (((b >> 7) & 7) << 4);
    int r = 2 * y0 + rw;
    gld_lds16(nb + (long)r * 7936 + sb, (char*)st + (r % 5) * 8192 + b);
  }
  __syncthreads();

  for (int iy = 0; iy < 5; iy++) {
    int y = y0 + iy;
    // ---- issue next-2-row stage early (hidden under stage-A MFMAs) ----
    if (iy < 4) {
#pragma unroll
      for (int i = 0; i < 4; i++) {
        int c = i * 256 + t;              // 1024 = 2 rows * 512 chunks
        int rw = c >> 9;                  // wave-uniform
        int b = (c & 511) * 16;
        int sb = b ^ (((b >> 7) & 7) << 4);
        int r = 2 * y + 3 + rw;           // rows 2y+3, 2y+4
        gld_lds16(nb + (long)r * 7936 + sb,
                  (char*)st + (r % 5) * 8192 + b);
      }
    }

    // ---- stage A: conv2 3x3 s2, 32->64, from LDS ring ----
    f32x16 acc;
#pragma unroll
    for (int i = 0; i < 16; i++) acc[i] = 0.f;
#pragma unroll
    for (int ky = 0; ky < 3; ky++) {
      int r = 2 * y + ky;
      int sb5 = (r % 5) * 4096;
#pragma unroll
      for (int kx = 0; kx < 3; kx++) {
#pragma unroll
        for (int c = 0; c < 2; c++) {
          bf16x8 av = *(const bf16x8*)(st + sb5 + usofs[kx][c]);
          acc = __builtin_amdgcn_mfma_f32_32x32x16_bf16(av, wA[ky * 3 + kx][c],
                                                        acc, 0, 0, 0);
        }
      }
    }
#pragma unroll
    for (int r = 0; r < 16; r++) {
      int row = (r & 3) + 8 * (r >> 2) + 4 * half;
      tile[(wm * 32 + row) * TS + oc] = f2bf(fmaxf(fmaf(acc[r], al1, be1), 0.f));
    }
    __syncthreads();   // tile ready; also drains prefetch vmcnt (has cover)

    // ---- conv3 1x1 64->128 + BN/ReLU + GAP (wB from L2 each iter) ----
    const US* ab = tile + (pt * 32 + lane31) * TS + half * 8;
    bf16x8 af[4];
#pragma unroll
    for (int c = 0; c < 4; c++) af[c] = *(const bf16x8*)(ab + c * 16);

#pragma unroll
    for (int nt = 0; nt < 2; nt++) {
      int oc2 = (og * 2 + nt) * 32 + lane31;
      const US* bb = wt2 + oc2 * 64 + half * 8;
      f32x16 acc2;
#pragma unroll
      for (int i = 0; i < 16; i++) acc2[i] = 0.f;
#pragma unroll
      for (int c = 0; c < 4; c++) {
        bf16x8 bv = *(const bf16x8*)(bb + c * 16);
        acc2 = __builtin_amdgcn_mfma_f32_32x32x16_bf16(af[c], bv, acc2,
                                                       0, 0, 0);
      }
      float s = 0.f;
      if (pt == 0) {
#pragma unroll
        for (int r = 0; r < 16; r++) s += fmaxf(fmaf(acc2[r], al2[nt], be2[nt]), 0.f);
      } else {
#pragma unroll
        for (int r = 0; r < 16; r++) {
          int row = (r & 3) + 8 * (r >> 2) + 4 * half;
          if (32 + row < 60) s += fmaxf(fmaf(acc2[r], al2[nt], be2[nt]), 0.f);
        }
      }
      s += __shfl_xor(s, 32);
      if (half == 0) atomicAdd(gap + n * C3_ + oc2, s);
    }
    __syncthreads();   // protect tile + ring slots for next iteration
  }
}

// ---------------------------------------------------------------------------
// K4 (R15, unchanged): head — 8 n's per block, wh reused. grid (5, 8).
// ---------------------------------------------------------------------------
__global__ __launch_bounds__(256) void k4_head(
    const float* __restrict__ gap, const float* __restrict__ wh,
    const float* __restrict__ alpha, const float* __restrict__ beta,
    float* __restrict__ out) {
  __shared__ float g[8 * C3_];
  int n0 = blockIdx.y * 8;
  int t = threadIdx.x;
  for (int e = t; e < 8 * C3_; e += 256)
    g[e] = gap[n0 * C3_ + e] * (1.f / 3600.f);
  __syncthreads();
  int o = blockIdx.x * 256 + t;
  const float* wr = wh + (long)o * C3_;
  float acc[8];
#pragma unroll
  for (int i = 0; i < 8; i++) acc[i] = 0.f;
#pragma unroll 4
  for (int c = 0; c < C3_; c += 4) {
    float4 wv = *(const float4*)(wr + c);
#pragma unroll
    for (int i = 0; i < 8; i++) {
      const float* gi = g + i * C3_ + c;
      acc[i] = fmaf(wv.x, gi[0], acc[i]);
      acc[i] = fmaf(wv.y, gi[1], acc[i]);
      acc[i] = fmaf(wv.z, gi[2], acc[i]);
      acc[i] = fmaf(wv.w, gi[3], acc[i]);
    }
  }
  float al = alpha[o], be = beta[o];
#pragma unroll
  for (int i = 0; i < 8; i++)
    out[(n0 + i) * HEAD_ + o] = fmaxf(fmaf(acc[i], al, be), 0.f);
}

// ---------------------------------------------------------------------------
extern "C" void kernel_launch(void* const* d_in, const int* in_sizes, int n_in,
                              void* d_out, int out_size, void* d_ws,
                              size_t ws_size, hipStream_t stream) {
  const float* x      = (const float*)d_in[0];
  const float* w_stem = (const float*)d_in[1];
  const float* a_stem = (const float*)d_in[2];
  const float* b_stem = (const float*)d_in[3];
  const float* w1     = (const float*)d_in[4];
  const float* a1     = (const float*)d_in[5];
  const float* b1     = (const float*)d_in[6];
  const float* w2     = (const float*)d_in[7];
  const float* a2     = (const float*)d_in[8];
  const float* b2     = (const float*)d_in[9];
  const float* wh     = (const float*)d_in[10];
  const float* ah     = (const float*)d_in[11];
  const float* bh     = (const float*)d_in[12];
  float* out = (float*)d_out;

  US* h1q = (US*)d_ws;                                   // 64*122*3968
  US* wt1 = h1q + (size_t)N_ * 122 * H1Q_ROW;            // 9*64*32
  US* wt2 = wt1 + 9 * 64 * 32;                           // 128*64
  US* wt0 = wt2 + C3_ * C2_;                             // 32*32
  float* gap = (float*)(wt0 + 1024);                     // 64*128 f32

  {  // K0: weights + gap only (h1q pads handled by k1)
    int total = 18432 + 8192 + 1024 + 8192;              // 35840
    k0_prep<<<(total + 255) / 256, 256, 0, stream>>>(w1, w2, w_stem,
                                                     wt1, wt2, wt0, gap);
  }
  {  // K1 MFMA stem + pad writes: grid (121, 64)
    dim3 grid(H1_ + 1, N_);
    k1_mfma<<<grid, 256, 0, stream>>>(x, wt0, a_stem, b_stem, h1q);
  }
  {  // K2 ring-5 @ 3 blocks/CU, wB un-hoisted
    dim3 grid(8, 96);
    k2_fused<<<grid, 256, 0, stream>>>(h1q, wt1, wt2, a1, b1, a2, b2, gap);
  }
  {  // K4: 8 n's per block, wh reused
    dim3 grid(HEAD_ / 256, 8);
    k4_head<<<grid, 256, 0, stream>>>(gap, wh, ah, bh, out);
  }
}

// Round 11
// 147.467 us; speedup vs baseline: 1.0269x; 1.0269x over previous
//
#include <hip/hip_runtime.h>

#define N_    64
#define HW_   240
#define H1_   120
#define H2_   60
#define C0_   3
#define C1_   32
#define C2_   64
#define C3_   128
#define HEAD_ 1280

typedef unsigned short US;
typedef short bf16x8 __attribute__((ext_vector_type(8)));
typedef float f32x16 __attribute__((ext_vector_type(16)));

__device__ __forceinline__ US f2bf(float f) {
  union { float f; unsigned u; } v; v.f = f;
  unsigned r = v.u + 0x7FFF + ((v.u >> 16) & 1);  // RNE
  return (US)(r >> 16);
}

// packed RNE f32x2 -> bf16x2 (bit-identical to f2bf for finite values)
__device__ __forceinline__ unsigned cvt_pk_bf16(float lo, float hi) {
  unsigned r;
  asm("v_cvt_pk_bf16_f32 %0, %1, %2" : "=v"(r) : "v"(lo), "v"(hi));
  return r;
}

// h1q parity-split padded NHWC bf16: [n][row 122][parity 2][xh 62][32ch].
// h1 pixel (gy,gx): row = gy+1; gx even=2m -> plane0[m]; gx odd=2m-1 -> plane1[m].
// Pad liveness (audited R8): k2 reads rows 0..120 only; live pads = row 0 +
// p1 m=0 chunk of rows 1..120 — written by k1; k0 doesn't touch h1q.
#define H1Q_ROW 3968
#define H1Q_PL  1984

__device__ __forceinline__ void gld_lds16(const void* g, void* l) {
  __builtin_amdgcn_global_load_lds(
      (const __attribute__((address_space(1))) unsigned int*)g,
      (__attribute__((address_space(3))) unsigned int*)l, 16, 0, 0);
}

// ---------------------------------------------------------------------------
// K0 (R8): weight prep + gap zero ONLY.
// ---------------------------------------------------------------------------
__global__ __launch_bounds__(256) void k0_prep(
    const float* __restrict__ w1, const float* __restrict__ w2,
    const float* __restrict__ w0,
    US* __restrict__ wt1, US* __restrict__ wt2,
    US* __restrict__ wt0, float* __restrict__ gap) {
  int gid = blockIdx.x * 256 + threadIdx.x;
  if (gid < 18432) {
    int e = gid;                              // w1 flat [oc][ic][ky][kx]
    int oc = e / 288, ic = (e / 9) % 32, ky = (e / 3) % 3, kx = e % 3;
    wt1[((ky * 3 + kx) * 64 + oc) * 32 + ic] = f2bf(w1[e]);
  } else if (gid < 18432 + 8192) {
    int e = gid - 18432;
    wt2[e] = f2bf(w2[e]);
  } else if (gid < 18432 + 8192 + 1024) {
    int e = gid - (18432 + 8192);             // e = oc*32 + k
    int oc = e >> 5, k = e & 31;
    wt0[e] = (k < 27) ? f2bf(w0[oc * 27 + k]) : (US)0;
  } else if (gid < 18432 + 8192 + 1024 + 8192) {
    gap[gid - (18432 + 8192 + 1024)] = 0.f;
  }
}

// ---------------------------------------------------------------------------
// K1 (R10 = R8 + packed A-fragment converts): stem conv 3->32 via MFMA
// im2col, 1 output row per block, global_load_lds x staging, pad-writing.
// Grid (121, 64). The 16 manual f2bf in the A-fragment path are replaced by
// 8 v_cvt_pk_bf16_f32 (RNE, bit-identical) — ~70 fewer VALU ops/thread
// between the LDS gather and the MFMAs.
// ---------------------------------------------------------------------------
#define XSW 248
__global__ __launch_bounds__(256) void k1_mfma(
    const float* __restrict__ x, const US* __restrict__ wt0,
    const float* __restrict__ alpha, const float* __restrict__ beta,
    US* __restrict__ h1q) {
  __shared__ __align__(16) float xs[3 * 3 * XSW];  // [seg=ic*3+r][248]
  __shared__ US ot[128 * 32];         // [px][oc] bf16
  int y = blockIdx.x, n = blockIdx.y;
  int t = threadIdx.x, w = t >> 6, l = t & 63;

  if (y == 120) {                     // zero pad row 0 (whole row, 3968 US)
    uint4 z; z.x = z.y = z.z = z.w = 0u;
    long base = (long)(n * 122) * H1Q_ROW;
    for (int u = t; u < 496; u += 256)
      *(uint4*)(h1q + base + (long)u * 8) = z;
    return;
  }

  long rowb = ((long)(n * 122 + y + 1)) * H1Q_ROW;
  if (t < 4) {                        // zero own row's p1 m=0 pad chunk
    uint4 z; z.x = z.y = z.z = z.w = 0u;
    *(uint4*)(h1q + rowb + H1Q_PL + t * 8) = z;
  }

  int iy0 = 2 * y - 1;
  const float* xn = x + (long)n * C0_ * HW_ * HW_;

  // boundary zeros: cols 0..3 and 244..247 per seg
  if (t < 18) {
    int seg = t >> 1, end = t & 1;
    float4 z; z.x = z.y = z.z = z.w = 0.f;
    *(float4*)(xs + seg * XSW + (end ? 244 : 0)) = z;
  }
  // iy<0 rows (only y==0, segs r==0): pre-zero interior
  if (y == 0) {
    float4 z; z.x = z.y = z.z = z.w = 0.f;
    for (int e = t; e < 180; e += 256) {
      int m = e % 60, icz = e / 60;
      *(float4*)(xs + (icz * 3) * XSW + 4 + 4 * m) = z;
    }
  }
  __syncthreads();   // zeros visible before async staging overlaps

  // async stage: seg (wave-uniform) = w, w+4, w+8; 60 lanes x 16 B each
  for (int sgi = w; sgi < 9; sgi += 4) {
    int ic = sgi / 3, r = sgi - (sgi / 3) * 3;
    int iy = iy0 + r;                  // wave-uniform
    if (iy >= 0 && l < 60)
      gld_lds16((const char*)(xn + (long)ic * HW_ * HW_ + (long)iy * HW_) +
                    l * 16,
                (char*)(xs + sgi * XSW + 4) + l * 16);
  }
  __syncthreads();   // drains vmcnt

  int wv = w;
  int lane31 = l & 31, half = l >> 5;
  int ox = wv * 32 + lane31;
  int oxc = ox < H1_ ? ox : (H1_ - 1);

  // A fragments: k = m*16 + half*8 + j; value = xs[seg(k)][3 + 2*oxc + kx]
  float fa[16];
#pragma unroll
  for (int m = 0; m < 2; m++)
#pragma unroll
    for (int j = 0; j < 8; j++) {
      int k = m * 16 + half * 8 + j;
      float v = 0.f;
      if (k < 27) {
        int ic = k / 9, rem = k - ic * 9;
        int ky = rem / 3, kx = rem - ky * 3;
        v = xs[(ic * 3 + ky) * XSW + 3 + 2 * oxc + kx];
      }
      fa[m * 8 + j] = v;
    }
  union { unsigned u[4]; bf16x8 v; } pa0, pa1;
#pragma unroll
  for (int j = 0; j < 4; j++) {
    pa0.u[j] = cvt_pk_bf16(fa[2 * j], fa[2 * j + 1]);
    pa1.u[j] = cvt_pk_bf16(fa[8 + 2 * j], fa[9 + 2 * j]);
  }
  bf16x8 a0 = pa0.v, a1 = pa1.v;
  const US* wb = wt0 + lane31 * 32 + half * 8;   // oc = lane31
  bf16x8 b0 = *(const bf16x8*)(wb);
  bf16x8 b1 = *(const bf16x8*)(wb + 16);

  f32x16 acc;
#pragma unroll
  for (int i = 0; i < 16; i++) acc[i] = 0.f;
  acc = __builtin_amdgcn_mfma_f32_32x32x16_bf16(a0, b0, acc, 0, 0, 0);
  acc = __builtin_amdgcn_mfma_f32_32x32x16_bf16(a1, b1, acc, 0, 0, 0);

  int oc = lane31;
  float al = alpha[oc], be = beta[oc];
#pragma unroll
  for (int r = 0; r < 16; r++) {
    int row = (r & 3) + 8 * (r >> 2) + 4 * half;   // px within tile
    float v = fmaxf(fmaf(acc[r], al, be), 0.f);
    ot[(wv * 32 + row) * 32 + oc] = f2bf(v);
  }
  __syncthreads();

  // store 120 px * 64 B as parity-split full chunks; 480 uint4 total
  for (int u = t; u < 480; u += 256) {
    int px = u >> 2, q = u & 3;
    int pl = px & 1;
    int m = (px + 1) >> 1;
    long addr = rowb + (pl ? H1Q_PL : 0) + (long)m * 32 + q * 8;
    *(uint4*)(h1q + addr) = *(const uint4*)(ot + px * 32 + q * 8);
  }
}

// ---------------------------------------------------------------------------
// K2 (R10 = R16-exact + register-GAP): persistent-row pipelined fused
// conv2+conv3+GAP. grid (8,64) = 512 blocks = 2/CU, ring-6 (the proven
// config; ring-5@3/CU, counted-vmcnt, and fusion all regressed). Only
// change: GAP partials accumulate in gsum[2] registers, ONE atomic commit
// per block at the end (2048 -> 512 atomics).
// ---------------------------------------------------------------------------
#define TS 72
__global__ __launch_bounds__(256, 2) void k2_fused(
    const US* __restrict__ h1q, const US* __restrict__ wt1,
    const US* __restrict__ wt2,
    const float* __restrict__ a1, const float* __restrict__ b1,
    const float* __restrict__ a2, const float* __restrict__ b2,
    float* __restrict__ gap) {
  __shared__ __align__(16) US st[6 * 4096];    // 49152 B: 6 row-slots (swz)
  __shared__ __align__(16) US tile[64 * TS];   // 9216 B: conv2 out [px][oc]
  int t = threadIdx.x, w = t >> 6, l = t & 63;
  int lane31 = l & 31, half = l >> 5;

  // XCD x (= blockIdx.x, x-major dispatch) handles n in [8x, 8x+8)
  int n = 8 * blockIdx.x + (blockIdx.y & 7);
  int bxr = blockIdx.y >> 3;                   // row-group 0..7
  int ny = bxr < 4 ? 8 : 7;
  int y0 = bxr < 4 ? bxr * 8 : 32 + (bxr - 4) * 7;

  const char* nb = (const char*)(h1q + (long)(n * 122) * H1Q_ROW);

  // ---- hoist all weights / BN params to registers (loop-invariant) ----
  int wm = w & 1, wn = w >> 1;                 // stage-A roles
  int oc = wn * 32 + lane31;
  int pt = w & 1, og = w >> 1;                 // conv3 roles
  bf16x8 wA[9][2];
#pragma unroll
  for (int kk = 0; kk < 9; kk++)
#pragma unroll
    for (int c = 0; c < 2; c++)
      wA[kk][c] = *(const bf16x8*)(wt1 + (kk * 64 + oc) * 32 + half * 8 + c * 16);
  bf16x8 wB[2][4];
  float al2[2], be2[2];
#pragma unroll
  for (int nt = 0; nt < 2; nt++) {
    int oc2 = (og * 2 + nt) * 32 + lane31;
#pragma unroll
    for (int c = 0; c < 4; c++)
      wB[nt][c] = *(const bf16x8*)(wt2 + oc2 * 64 + half * 8 + c * 16);
    al2[nt] = a2[oc2]; be2[nt] = b2[oc2];
  }
  float al1 = a1[oc], be1 = b1[oc];
  float gsum[2] = {0.f, 0.f};

  // per-thread invariant A-read offsets (swizzled, within-row US units)
  int px = wm * 32 + lane31;
  int xx = px < 60 ? px : 59;
  int abase = xx * 32 + half * 8;
  int usofs[3][2];
#pragma unroll
  for (int kx = 0; kx < 3; kx++)
#pragma unroll
    for (int c = 0; c < 2; c++) {
      int uo = (kx == 1 ? 0 : (kx == 0 ? 1984 : 2016)) + abase + c * 16;
      usofs[kx][c] = uo ^ (((uo >> 6) & 7) << 3);
    }

  // ---- prologue: stage rows 2y0..2y0+2, 512 chunks (8 KB) per row ----
#pragma unroll
  for (int i = 0; i < 6; i++) {
    int c = i * 256 + t;                  // 1536 = 3 rows * 512 chunks
    int rw = c >> 9;                      // wave-uniform (512 % 64 == 0)
    int b = (c & 511) * 16;
    int sb = b ^ (((b >> 7) & 7) << 4);
    int r = 2 * y0 + rw;
    gld_lds16(nb + (long)r * 7936 + sb, (char*)st + (r % 6) * 8192 + b);
  }
  __syncthreads();

  for (int iy = 0; iy < ny; iy++) {
    int y = y0 + iy;
    // ---- issue next-2-row stage early (hidden under stage-A MFMAs) ----
    if (iy + 1 < ny) {
#pragma unroll
      for (int i = 0; i < 4; i++) {
        int c = i * 256 + t;              // 1024 = 2 rows * 512 chunks
        int rw = c >> 9;                  // wave-uniform
        int b = (c & 511) * 16;
        int sb = b ^ (((b >> 7) & 7) << 4);
        int r = 2 * y + 3 + rw;           // rows 2y+3, 2y+4 (slots disjoint
        gld_lds16(nb + (long)r * 7936 + sb,  // from compute rows 2y..2y+2)
                  (char*)st + (r % 6) * 8192 + b);
      }
    }

    // ---- stage A: conv2 3x3 s2, 32->64, from LDS ring ----
    f32x16 acc;
#pragma unroll
    for (int i = 0; i < 16; i++) acc[i] = 0.f;
#pragma unroll
    for (int ky = 0; ky < 3; ky++) {
      int r = 2 * y + ky;
      int sb6 = (r % 6) * 4096;
#pragma unroll
      for (int kx = 0; kx < 3; kx++) {
#pragma unroll
        for (int c = 0; c < 2; c++) {
          bf16x8 av = *(const bf16x8*)(st + sb6 + usofs[kx][c]);
          acc = __builtin_amdgcn_mfma_f32_32x32x16_bf16(av, wA[ky * 3 + kx][c],
                                                        acc, 0, 0, 0);
        }
      }
    }
#pragma unroll
    for (int r = 0; r < 16; r++) {
      int row = (r & 3) + 8 * (r >> 2) + 4 * half;
      tile[(wm * 32 + row) * TS + oc] = f2bf(fmaxf(fmaf(acc[r], al1, be1), 0.f));
    }
    __syncthreads();   // tile ready; also drains prefetch vmcnt (has cover)

    // ---- conv3 1x1 64->128 + BN/ReLU + GAP (register accumulation) ----
    const US* ab = tile + (pt * 32 + lane31) * TS + half * 8;
    bf16x8 af[4];
#pragma unroll
    for (int c = 0; c < 4; c++) af[c] = *(const bf16x8*)(ab + c * 16);

#pragma unroll
    for (int nt = 0; nt < 2; nt++) {
      f32x16 acc2;
#pragma unroll
      for (int i = 0; i < 16; i++) acc2[i] = 0.f;
#pragma unroll
      for (int c = 0; c < 4; c++)
        acc2 = __builtin_amdgcn_mfma_f32_32x32x16_bf16(af[c], wB[nt][c], acc2,
                                                       0, 0, 0);
      float s = 0.f;
      if (pt == 0) {
#pragma unroll
        for (int r = 0; r < 16; r++) s += fmaxf(fmaf(acc2[r], al2[nt], be2[nt]), 0.f);
      } else {
#pragma unroll
        for (int r = 0; r < 16; r++) {
          int row = (r & 3) + 8 * (r >> 2) + 4 * half;
          if (32 + row < 60) s += fmaxf(fmaf(acc2[r], al2[nt], be2[nt]), 0.f);
        }
      }
      gsum[nt] += s;
    }
    __syncthreads();   // protect tile + ring slots for next iteration
  }

  // ---- one atomic commit per block ----
#pragma unroll
  for (int nt = 0; nt < 2; nt++) {
    float s = gsum[nt];
    s += __shfl_xor(s, 32);
    if (half == 0) {
      int oc2 = (og * 2 + nt) * 32 + lane31;
      atomicAdd(gap + n * C3_ + oc2, s);
    }
  }
}

// ---------------------------------------------------------------------------
// K4 (R15, unchanged): head — 8 n's per block, wh reused. grid (5, 8).
// ---------------------------------------------------------------------------
__global__ __launch_bounds__(256) void k4_head(
    const float* __restrict__ gap, const float* __restrict__ wh,
    const float* __restrict__ alpha, const float* __restrict__ beta,
    float* __restrict__ out) {
  __shared__ float g[8 * C3_];
  int n0 = blockIdx.y * 8;
  int t = threadIdx.x;
  for (int e = t; e < 8 * C3_; e += 256)
    g[e] = gap[n0 * C3_ + e] * (1.f / 3600.f);
  __syncthreads();
  int o = blockIdx.x * 256 + t;
  const float* wr = wh + (long)o * C3_;
  float acc[8];
#pragma unroll
  for (int i = 0; i < 8; i++) acc[i] = 0.f;
#pragma unroll 4
  for (int c = 0; c < C3_; c += 4) {
    float4 wv = *(const float4*)(wr + c);
#pragma unroll
    for (int i = 0; i < 8; i++) {
      const float* gi = g + i * C3_ + c;
      acc[i] = fmaf(wv.x, gi[0], acc[i]);
      acc[i] = fmaf(wv.y, gi[1], acc[i]);
      acc[i] = fmaf(wv.z, gi[2], acc[i]);
      acc[i] = fmaf(wv.w, gi[3], acc[i]);
    }
  }
  float al = alpha[o], be = beta[o];
#pragma unroll
  for (int i = 0; i < 8; i++)
    out[(n0 + i) * HEAD_ + o] = fmaxf(fmaf(acc[i], al, be), 0.f);
}

// ---------------------------------------------------------------------------
extern "C" void kernel_launch(void* const* d_in, const int* in_sizes, int n_in,
                              void* d_out, int out_size, void* d_ws,
                              size_t ws_size, hipStream_t stream) {
  const float* x      = (const float*)d_in[0];
  const float* w_stem = (const float*)d_in[1];
  const float* a_stem = (const float*)d_in[2];
  const float* b_stem = (const float*)d_in[3];
  const float* w1     = (const float*)d_in[4];
  const float* a1     = (const float*)d_in[5];
  const float* b1     = (const float*)d_in[6];
  const float* w2     = (const float*)d_in[7];
  const float* a2     = (const float*)d_in[8];
  const float* b2     = (const float*)d_in[9];
  const float* wh     = (const float*)d_in[10];
  const float* ah     = (const float*)d_in[11];
  const float* bh     = (const float*)d_in[12];
  float* out = (float*)d_out;

  US* h1q = (US*)d_ws;                                   // 64*122*3968
  US* wt1 = h1q + (size_t)N_ * 122 * H1Q_ROW;            // 9*64*32
  US* wt2 = wt1 + 9 * 64 * 32;                           // 128*64
  US* wt0 = wt2 + C3_ * C2_;                             // 32*32
  float* gap = (float*)(wt0 + 1024);                     // 64*128 f32

  {  // K0: weights + gap only (h1q pads handled by k1)
    int total = 18432 + 8192 + 1024 + 8192;              // 35840
    k0_prep<<<(total + 255) / 256, 256, 0, stream>>>(w1, w2, w_stem,
                                                     wt1, wt2, wt0, gap);
  }
  {  // K1 MFMA stem + pad writes: grid (121, 64)
    dim3 grid(H1_ + 1, N_);
    k1_mfma<<<grid, 256, 0, stream>>>(x, wt0, a_stem, b_stem, h1q);
  }
  {  // K2 persistent-row pipelined conv2+conv3+GAP (ring-6, 2/CU, reg-GAP)
    dim3 grid(8, N_);
    k2_fused<<<grid, 256, 0, stream>>>(h1q, wt1, wt2, a1, b1, a2, b2, gap);
  }
  {  // K4: 8 n's per block, wh reused
    dim3 grid(HEAD_ / 256, 8);
    k4_head<<<grid, 256, 0, stream>>>(gap, wh, ah, bh, out);
  }
}

// Round 12
// 146.026 us; speedup vs baseline: 1.0370x; 1.0099x over previous
//
#include <hip/hip_runtime.h>

#define N_    64
#define HW_   240
#define H1_   120
#define H2_   60
#define C0_   3
#define C1_   32
#define C2_   64
#define C3_   128
#define HEAD_ 1280

typedef unsigned short US;
typedef short bf16x8 __attribute__((ext_vector_type(8)));
typedef float f32x16 __attribute__((ext_vector_type(16)));

__device__ __forceinline__ US f2bf(float f) {
  union { float f; unsigned u; } v; v.f = f;
  unsigned r = v.u + 0x7FFF + ((v.u >> 16) & 1);  // RNE
  return (US)(r >> 16);
}

// packed RNE f32x2 -> bf16x2 (bit-identical to f2bf for finite values)
__device__ __forceinline__ unsigned cvt_pk_bf16(float lo, float hi) {
  unsigned r;
  asm("v_cvt_pk_bf16_f32 %0, %1, %2" : "=v"(r) : "v"(lo), "v"(hi));
  return r;
}

// h1q parity-split padded NHWC bf16: [n][row 122][parity 2][xh 62][32ch].
// h1 pixel (gy,gx): row = gy+1; gx even=2m -> plane0[m]; gx odd=2m-1 -> plane1[m].
// Pad liveness (audited R8): k2 reads rows 0..120 only; live pads = row 0 +
// p1 m=0 chunk of rows 1..120 — written by k1; k0 doesn't touch h1q.
#define H1Q_ROW 3968
#define H1Q_PL  1984

__device__ __forceinline__ void gld_lds16(const void* g, void* l) {
  __builtin_amdgcn_global_load_lds(
      (const __attribute__((address_space(1))) unsigned int*)g,
      (__attribute__((address_space(3))) unsigned int*)l, 16, 0, 0);
}

// ---------------------------------------------------------------------------
// K0 (R8): weight prep + gap zero ONLY.
// ---------------------------------------------------------------------------
__global__ __launch_bounds__(256) void k0_prep(
    const float* __restrict__ w1, const float* __restrict__ w2,
    const float* __restrict__ w0,
    US* __restrict__ wt1, US* __restrict__ wt2,
    US* __restrict__ wt0, float* __restrict__ gap) {
  int gid = blockIdx.x * 256 + threadIdx.x;
  if (gid < 18432) {
    int e = gid;                              // w1 flat [oc][ic][ky][kx]
    int oc = e / 288, ic = (e / 9) % 32, ky = (e / 3) % 3, kx = e % 3;
    wt1[((ky * 3 + kx) * 64 + oc) * 32 + ic] = f2bf(w1[e]);
  } else if (gid < 18432 + 8192) {
    int e = gid - 18432;
    wt2[e] = f2bf(w2[e]);
  } else if (gid < 18432 + 8192 + 1024) {
    int e = gid - (18432 + 8192);             // e = oc*32 + k
    int oc = e >> 5, k = e & 31;
    wt0[e] = (k < 27) ? f2bf(w0[oc * 27 + k]) : (US)0;
  } else if (gid < 18432 + 8192 + 1024 + 8192) {
    gap[gid - (18432 + 8192 + 1024)] = 0.f;
  }
}

// ---------------------------------------------------------------------------
// K1 (R12 = R10 + packed C-write converts): stem conv 3->32 via MFMA
// im2col, 1 output row per block, global_load_lds x staging, pad-writing.
// Grid (121, 64). Both f2bf sites now use v_cvt_pk_bf16_f32 (RNE,
// bit-identical): A-fragments (R11) and the C-write epilogue (this round,
// pairs r/r+1 -> rows row0/row0+1 in the same quad; 80 -> ~24 VALU ops).
// ---------------------------------------------------------------------------
#define XSW 248
__global__ __launch_bounds__(256) void k1_mfma(
    const float* __restrict__ x, const US* __restrict__ wt0,
    const float* __restrict__ alpha, const float* __restrict__ beta,
    US* __restrict__ h1q) {
  __shared__ __align__(16) float xs[3 * 3 * XSW];  // [seg=ic*3+r][248]
  __shared__ US ot[128 * 32];         // [px][oc] bf16
  int y = blockIdx.x, n = blockIdx.y;
  int t = threadIdx.x, w = t >> 6, l = t & 63;

  if (y == 120) {                     // zero pad row 0 (whole row, 3968 US)
    uint4 z; z.x = z.y = z.z = z.w = 0u;
    long base = (long)(n * 122) * H1Q_ROW;
    for (int u = t; u < 496; u += 256)
      *(uint4*)(h1q + base + (long)u * 8) = z;
    return;
  }

  long rowb = ((long)(n * 122 + y + 1)) * H1Q_ROW;
  if (t < 4) {                        // zero own row's p1 m=0 pad chunk
    uint4 z; z.x = z.y = z.z = z.w = 0u;
    *(uint4*)(h1q + rowb + H1Q_PL + t * 8) = z;
  }

  int iy0 = 2 * y - 1;
  const float* xn = x + (long)n * C0_ * HW_ * HW_;

  // boundary zeros: cols 0..3 and 244..247 per seg
  if (t < 18) {
    int seg = t >> 1, end = t & 1;
    float4 z; z.x = z.y = z.z = z.w = 0.f;
    *(float4*)(xs + seg * XSW + (end ? 244 : 0)) = z;
  }
  // iy<0 rows (only y==0, segs r==0): pre-zero interior
  if (y == 0) {
    float4 z; z.x = z.y = z.z = z.w = 0.f;
    for (int e = t; e < 180; e += 256) {
      int m = e % 60, icz = e / 60;
      *(float4*)(xs + (icz * 3) * XSW + 4 + 4 * m) = z;
    }
  }
  __syncthreads();   // zeros visible before async staging overlaps

  // async stage: seg (wave-uniform) = w, w+4, w+8; 60 lanes x 16 B each
  for (int sgi = w; sgi < 9; sgi += 4) {
    int ic = sgi / 3, r = sgi - (sgi / 3) * 3;
    int iy = iy0 + r;                  // wave-uniform
    if (iy >= 0 && l < 60)
      gld_lds16((const char*)(xn + (long)ic * HW_ * HW_ + (long)iy * HW_) +
                    l * 16,
                (char*)(xs + sgi * XSW + 4) + l * 16);
  }
  __syncthreads();   // drains vmcnt

  int wv = w;
  int lane31 = l & 31, half = l >> 5;
  int ox = wv * 32 + lane31;
  int oxc = ox < H1_ ? ox : (H1_ - 1);

  // A fragments: k = m*16 + half*8 + j; value = xs[seg(k)][3 + 2*oxc + kx]
  float fa[16];
#pragma unroll
  for (int m = 0; m < 2; m++)
#pragma unroll
    for (int j = 0; j < 8; j++) {
      int k = m * 16 + half * 8 + j;
      float v = 0.f;
      if (k < 27) {
        int ic = k / 9, rem = k - ic * 9;
        int ky = rem / 3, kx = rem - ky * 3;
        v = xs[(ic * 3 + ky) * XSW + 3 + 2 * oxc + kx];
      }
      fa[m * 8 + j] = v;
    }
  union { unsigned u[4]; bf16x8 v; } pa0, pa1;
#pragma unroll
  for (int j = 0; j < 4; j++) {
    pa0.u[j] = cvt_pk_bf16(fa[2 * j], fa[2 * j + 1]);
    pa1.u[j] = cvt_pk_bf16(fa[8 + 2 * j], fa[9 + 2 * j]);
  }
  bf16x8 a0 = pa0.v, a1 = pa1.v;
  const US* wb = wt0 + lane31 * 32 + half * 8;   // oc = lane31
  bf16x8 b0 = *(const bf16x8*)(wb);
  bf16x8 b1 = *(const bf16x8*)(wb + 16);

  f32x16 acc;
#pragma unroll
  for (int i = 0; i < 16; i++) acc[i] = 0.f;
  acc = __builtin_amdgcn_mfma_f32_32x32x16_bf16(a0, b0, acc, 0, 0, 0);
  acc = __builtin_amdgcn_mfma_f32_32x32x16_bf16(a1, b1, acc, 0, 0, 0);

  int oc = lane31;
  float al = alpha[oc], be = beta[oc];
#pragma unroll
  for (int r = 0; r < 16; r += 2) {
    int row0 = (r & 3) + 8 * (r >> 2) + 4 * half;   // r even: row1 = row0+1
    float v0 = fmaxf(fmaf(acc[r], al, be), 0.f);
    float v1 = fmaxf(fmaf(acc[r + 1], al, be), 0.f);
    unsigned u = cvt_pk_bf16(v0, v1);
    ot[(wv * 32 + row0) * 32 + oc] = (US)u;
    ot[(wv * 32 + row0 + 1) * 32 + oc] = (US)(u >> 16);
  }
  __syncthreads();

  // store 120 px * 64 B as parity-split full chunks; 480 uint4 total
  for (int u = t; u < 480; u += 256) {
    int px = u >> 2, q = u & 3;
    int pl = px & 1;
    int m = (px + 1) >> 1;
    long addr = rowb + (pl ? H1Q_PL : 0) + (long)m * 32 + q * 8;
    *(uint4*)(h1q + addr) = *(const uint4*)(ot + px * 32 + q * 8);
  }
}

// ---------------------------------------------------------------------------
// K2 (R12 = R10 + packed tile-write converts): persistent-row pipelined
// fused conv2+conv3+GAP. grid (8,64) = 512 blocks = 2/CU, ring-6, reg-GAP.
// The 16 f2bf/thread/iter between conv2 MFMAs and the mid-iter barrier
// (critical path) become 8 cvt_pk + 8 shifts (~640 -> ~160 VALU ops over
// the kernel lifetime).
// ---------------------------------------------------------------------------
#define TS 72
__global__ __launch_bounds__(256, 2) void k2_fused(
    const US* __restrict__ h1q, const US* __restrict__ wt1,
    const US* __restrict__ wt2,
    const float* __restrict__ a1, const float* __restrict__ b1,
    const float* __restrict__ a2, const float* __restrict__ b2,
    float* __restrict__ gap) {
  __shared__ __align__(16) US st[6 * 4096];    // 49152 B: 6 row-slots (swz)
  __shared__ __align__(16) US tile[64 * TS];   // 9216 B: conv2 out [px][oc]
  int t = threadIdx.x, w = t >> 6, l = t & 63;
  int lane31 = l & 31, half = l >> 5;

  // XCD x (= blockIdx.x, x-major dispatch) handles n in [8x, 8x+8)
  int n = 8 * blockIdx.x + (blockIdx.y & 7);
  int bxr = blockIdx.y >> 3;                   // row-group 0..7
  int ny = bxr < 4 ? 8 : 7;
  int y0 = bxr < 4 ? bxr * 8 : 32 + (bxr - 4) * 7;

  const char* nb = (const char*)(h1q + (long)(n * 122) * H1Q_ROW);

  // ---- hoist all weights / BN params to registers (loop-invariant) ----
  int wm = w & 1, wn = w >> 1;                 // stage-A roles
  int oc = wn * 32 + lane31;
  int pt = w & 1, og = w >> 1;                 // conv3 roles
  bf16x8 wA[9][2];
#pragma unroll
  for (int kk = 0; kk < 9; kk++)
#pragma unroll
    for (int c = 0; c < 2; c++)
      wA[kk][c] = *(const bf16x8*)(wt1 + (kk * 64 + oc) * 32 + half * 8 + c * 16);
  bf16x8 wB[2][4];
  float al2[2], be2[2];
#pragma unroll
  for (int nt = 0; nt < 2; nt++) {
    int oc2 = (og * 2 + nt) * 32 + lane31;
#pragma unroll
    for (int c = 0; c < 4; c++)
      wB[nt][c] = *(const bf16x8*)(wt2 + oc2 * 64 + half * 8 + c * 16);
    al2[nt] = a2[oc2]; be2[nt] = b2[oc2];
  }
  float al1 = a1[oc], be1 = b1[oc];
  float gsum[2] = {0.f, 0.f};

  // per-thread invariant A-read offsets (swizzled, within-row US units)
  int px = wm * 32 + lane31;
  int xx = px < 60 ? px : 59;
  int abase = xx * 32 + half * 8;
  int usofs[3][2];
#pragma unroll
  for (int kx = 0; kx < 3; kx++)
#pragma unroll
    for (int c = 0; c < 2; c++) {
      int uo = (kx == 1 ? 0 : (kx == 0 ? 1984 : 2016)) + abase + c * 16;
      usofs[kx][c] = uo ^ (((uo >> 6) & 7) << 3);
    }

  // ---- prologue: stage rows 2y0..2y0+2, 512 chunks (8 KB) per row ----
#pragma unroll
  for (int i = 0; i < 6; i++) {
    int c = i * 256 + t;                  // 1536 = 3 rows * 512 chunks
    int rw = c >> 9;                      // wave-uniform (512 % 64 == 0)
    int b = (c & 511) * 16;
    int sb = b ^ (((b >> 7) & 7) << 4);
    int r = 2 * y0 + rw;
    gld_lds16(nb + (long)r * 7936 + sb, (char*)st + (r % 6) * 8192 + b);
  }
  __syncthreads();

  for (int iy = 0; iy < ny; iy++) {
    int y = y0 + iy;
    // ---- issue next-2-row stage early (hidden under stage-A MFMAs) ----
    if (iy + 1 < ny) {
#pragma unroll
      for (int i = 0; i < 4; i++) {
        int c = i * 256 + t;              // 1024 = 2 rows * 512 chunks
        int rw = c >> 9;                  // wave-uniform
        int b = (c & 511) * 16;
        int sb = b ^ (((b >> 7) & 7) << 4);
        int r = 2 * y + 3 + rw;           // rows 2y+3, 2y+4 (slots disjoint
        gld_lds16(nb + (long)r * 7936 + sb,  // from compute rows 2y..2y+2)
                  (char*)st + (r % 6) * 8192 + b);
      }
    }

    // ---- stage A: conv2 3x3 s2, 32->64, from LDS ring ----
    f32x16 acc;
#pragma unroll
    for (int i = 0; i < 16; i++) acc[i] = 0.f;
#pragma unroll
    for (int ky = 0; ky < 3; ky++) {
      int r = 2 * y + ky;
      int sb6 = (r % 6) * 4096;
#pragma unroll
      for (int kx = 0; kx < 3; kx++) {
#pragma unroll
        for (int c = 0; c < 2; c++) {
          bf16x8 av = *(const bf16x8*)(st + sb6 + usofs[kx][c]);
          acc = __builtin_amdgcn_mfma_f32_32x32x16_bf16(av, wA[ky * 3 + kx][c],
                                                        acc, 0, 0, 0);
        }
      }
    }
#pragma unroll
    for (int r = 0; r < 16; r += 2) {
      int row0 = (r & 3) + 8 * (r >> 2) + 4 * half;  // r even: row1 = row0+1
      float v0 = fmaxf(fmaf(acc[r], al1, be1), 0.f);
      float v1 = fmaxf(fmaf(acc[r + 1], al1, be1), 0.f);
      unsigned u = cvt_pk_bf16(v0, v1);
      tile[(wm * 32 + row0) * TS + oc] = (US)u;
      tile[(wm * 32 + row0 + 1) * TS + oc] = (US)(u >> 16);
    }
    __syncthreads();   // tile ready; also drains prefetch vmcnt (has cover)

    // ---- conv3 1x1 64->128 + BN/ReLU + GAP (register accumulation) ----
    const US* ab = tile + (pt * 32 + lane31) * TS + half * 8;
    bf16x8 af[4];
#pragma unroll
    for (int c = 0; c < 4; c++) af[c] = *(const bf16x8*)(ab + c * 16);

#pragma unroll
    for (int nt = 0; nt < 2; nt++) {
      f32x16 acc2;
#pragma unroll
      for (int i = 0; i < 16; i++) acc2[i] = 0.f;
#pragma unroll
      for (int c = 0; c < 4; c++)
        acc2 = __builtin_amdgcn_mfma_f32_32x32x16_bf16(af[c], wB[nt][c], acc2,
                                                       0, 0, 0);
      float s = 0.f;
      if (pt == 0) {
#pragma unroll
        for (int r = 0; r < 16; r++) s += fmaxf(fmaf(acc2[r], al2[nt], be2[nt]), 0.f);
      } else {
#pragma unroll
        for (int r = 0; r < 16; r++) {
          int row = (r & 3) + 8 * (r >> 2) + 4 * half;
          if (32 + row < 60) s += fmaxf(fmaf(acc2[r], al2[nt], be2[nt]), 0.f);
        }
      }
      gsum[nt] += s;
    }
    __syncthreads();   // protect tile + ring slots for next iteration
  }

  // ---- one atomic commit per block ----
#pragma unroll
  for (int nt = 0; nt < 2; nt++) {
    float s = gsum[nt];
    s += __shfl_xor(s, 32);
    if (half == 0) {
      int oc2 = (og * 2 + nt) * 32 + lane31;
      atomicAdd(gap + n * C3_ + oc2, s);
    }
  }
}

// ---------------------------------------------------------------------------
// K4 (R15, unchanged): head — 8 n's per block, wh reused. grid (5, 8).
// ---------------------------------------------------------------------------
__global__ __launch_bounds__(256) void k4_head(
    const float* __restrict__ gap, const float* __restrict__ wh,
    const float* __restrict__ alpha, const float* __restrict__ beta,
    float* __restrict__ out) {
  __shared__ float g[8 * C3_];
  int n0 = blockIdx.y * 8;
  int t = threadIdx.x;
  for (int e = t; e < 8 * C3_; e += 256)
    g[e] = gap[n0 * C3_ + e] * (1.f / 3600.f);
  __syncthreads();
  int o = blockIdx.x * 256 + t;
  const float* wr = wh + (long)o * C3_;
  float acc[8];
#pragma unroll
  for (int i = 0; i < 8; i++) acc[i] = 0.f;
#pragma unroll 4
  for (int c = 0; c < C3_; c += 4) {
    float4 wv = *(const float4*)(wr + c);
#pragma unroll
    for (int i = 0; i < 8; i++) {
      const float* gi = g + i * C3_ + c;
      acc[i] = fmaf(wv.x, gi[0], acc[i]);
      acc[i] = fmaf(wv.y, gi[1], acc[i]);
      acc[i] = fmaf(wv.z, gi[2], acc[i]);
      acc[i] = fmaf(wv.w, gi[3], acc[i]);
    }
  }
  float al = alpha[o], be = beta[o];
#pragma unroll
  for (int i = 0; i < 8; i++)
    out[(n0 + i) * HEAD_ + o] = fmaxf(fmaf(acc[i], al, be), 0.f);
}

// ---------------------------------------------------------------------------
extern "C" void kernel_launch(void* const* d_in, const int* in_sizes, int n_in,
                              void* d_out, int out_size, void* d_ws,
                              size_t ws_size, hipStream_t stream) {
  const float* x      = (const float*)d_in[0];
  const float* w_stem = (const float*)d_in[1];
  const float* a_stem = (const float*)d_in[2];
  const float* b_stem = (const float*)d_in[3];
  const float* w1     = (const float*)d_in[4];
  const float* a1     = (const float*)d_in[5];
  const float* b1     = (const float*)d_in[6];
  const float* w2     = (const float*)d_in[7];
  const float* a2     = (const float*)d_in[8];
  const float* b2     = (const float*)d_in[9];
  const float* wh     = (const float*)d_in[10];
  const float* ah     = (const float*)d_in[11];
  const float* bh     = (const float*)d_in[12];
  float* out = (float*)d_out;

  US* h1q = (US*)d_ws;                                   // 64*122*3968
  US* wt1 = h1q + (size_t)N_ * 122 * H1Q_ROW;            // 9*64*32
  US* wt2 = wt1 + 9 * 64 * 32;                           // 128*64
  US* wt0 = wt2 + C3_ * C2_;                             // 32*32
  float* gap = (float*)(wt0 + 1024);                     // 64*128 f32

  {  // K0: weights + gap only (h1q pads handled by k1)
    int total = 18432 + 8192 + 1024 + 8192;              // 35840
    k0_prep<<<(total + 255) / 256, 256, 0, stream>>>(w1, w2, w_stem,
                                                     wt1, wt2, wt0, gap);
  }
  {  // K1 MFMA stem + pad writes: grid (121, 64)
    dim3 grid(H1_ + 1, N_);
    k1_mfma<<<grid, 256, 0, stream>>>(x, wt0, a_stem, b_stem, h1q);
  }
  {  // K2 persistent-row pipelined conv2+conv3+GAP (ring-6, 2/CU, reg-GAP)
    dim3 grid(8, N_);
    k2_fused<<<grid, 256, 0, stream>>>(h1q, wt1, wt2, a1, b1, a2, b2, gap);
  }
  {  // K4: 8 n's per block, wh reused
    dim3 grid(HEAD_ / 256, 8);
    k4_head<<<grid, 256, 0, stream>>>(gap, wh, ah, bh, out);
  }
}